// Round 6
// baseline (347.910 us; speedup 1.0000x reference)
//
#include <hip/hip_runtime.h>
#include <stdint.h>

#define P 2048
#define R 65536
#define DD 512
#define BM 256
#define BN 256
#define BK 64
#define NT (DD / BK)   // 8 K-tiles

typedef __attribute__((ext_vector_type(8))) short short8;
typedef __attribute__((ext_vector_type(4))) float f32x4;
typedef __attribute__((ext_vector_type(16))) float f32x16;

__device__ inline unsigned short f2bf(float f) {
  unsigned int u = __float_as_uint(f);
  u += 0x7fffu + ((u >> 16) & 1u);   // round-to-nearest-even
  return (unsigned short)(u >> 16);
}

__device__ inline void gload_lds16(const void* g, void* l) {
  __builtin_amdgcn_global_load_lds(
      (const __attribute__((address_space(1))) unsigned int*)g,
      (__attribute__((address_space(3))) unsigned int*)l,
      16, 0, 0);
}

// ---- kernel 1: fp32 -> bf16 conversion + fp32 row norms; one wave per row,
//      grid-stride (2048 blocks, ~8 rows/wave) ----
__global__ __launch_bounds__(256) void k_convert(
    const float* __restrict__ pred, const float* __restrict__ cand,
    unsigned short* __restrict__ Abf, unsigned short* __restrict__ Bbf,
    float* __restrict__ nx, float* __restrict__ ny,
    unsigned int* __restrict__ minp)
{
  if (blockIdx.x == 0 && threadIdx.x == 0) *minp = 0x7f800000u; // +inf bits
  const int lane = threadIdx.x & 63;
  const int wv   = (blockIdx.x << 2) | (threadIdx.x >> 6);
  const int nw   = gridDim.x << 2;
  for (int gw = wv; gw < P + R; gw += nw) {
    const float* src; unsigned short* dst; float* np;
    if (gw < P) { src = pred + (size_t)gw * DD; dst = Abf + (size_t)gw * DD; np = nx + gw; }
    else { int r = gw - P; src = cand + (size_t)r * DD; dst = Bbf + (size_t)r * DD; np = ny + r; }
    const float4* s4 = ((const float4*)src) + lane * 2;
    float4 v0 = s4[0], v1 = s4[1];
    float ss = v0.x*v0.x + v0.y*v0.y + v0.z*v0.z + v0.w*v0.w
             + v1.x*v1.x + v1.y*v1.y + v1.z*v1.z + v1.w*v1.w;
    union { unsigned short h[8]; uint4 v; } pk;
    pk.h[0]=f2bf(v0.x); pk.h[1]=f2bf(v0.y); pk.h[2]=f2bf(v0.z); pk.h[3]=f2bf(v0.w);
    pk.h[4]=f2bf(v1.x); pk.h[5]=f2bf(v1.y); pk.h[6]=f2bf(v1.z); pk.h[7]=f2bf(v1.w);
    *(uint4*)(dst + (size_t)lane * 8) = pk.v;
    #pragma unroll
    for (int off = 32; off; off >>= 1) ss += __shfl_down(ss, off, 64);
    if (lane == 0) *np = ss;
  }
}

// ---- kernel 2: 256x256 bf16 MFMA GEMM (A·B^T), BK=64, 8 waves (2Mx4N),
//      32x32x16 MFMA, double-buffered LDS, *** SINGLE barrier per tile ***
//      (deep prefetch: vmcnt(0) drains loads issued a full tile earlier ->
//      free; stage issued after the barrier overlaps compute), counted-lgkm
//      k-step lookahead, setprio, XCD swizzle, re-derived conflict-free
//      XOR swizzle, fused min epilogue.
//
// LDS: per operand/buffer row-major [256][64] bf16; 16B-chunks of each row
// stored permuted: stored_chunk = data_chunk ^ (row&7) ^ (((row>>3)&3)<<1),
// applied on the GLOBAL source address (linear gload_lds dest, rule #21).
// Round-5's swizzle (^row&7 only) gave 1.26e7 bank conflicts on the 32x32
// read (stride-8 lane groups collapsed to 2 chunk slots); adding the
// ((row>>3)&3)<<1 term makes the 8 stored chunks distinct within BOTH
// contiguous-8 and stride-8 lane groups -> conflict-free under either HW
// grouping model (SQ_LDS_BANK_CONFLICT verifies).
//
// 32x32x16 fragments: A/B row = 32-aligned base + (lane&31), k-elems
// (lane>>5)*8 of the 16-wide k-step -> data chunk = ks*2 + (lane>>5);
// stored chunk = (2ks+h) ^ (lane&7) ^ (((lane>>3)&3)<<1).
// C/D layout (m74/m101): col = lane&31, row = (reg&3) + 8*(reg>>2) + 4*(lane>>5).
//
// Per-tile schedule (single barrier):
//   vmcnt(0)   [drains MY loads staged one tile ago -> buf s ready; ~free]
//   s_barrier  [ALL waves' buf-s loads landed; all waves done reading s^1]
//   STAGE(s^1, T+1)   [8 gload_lds, fly across the whole compute phase]
//   4 k-steps: READ(6 ds_read_b128) / lgkm(6) / 8 MFMA   [1-step lookahead]
__global__ __launch_bounds__(512, 2) void k_gemm_min(
    const unsigned short* __restrict__ Abf, const unsigned short* __restrict__ Bbf,
    const float* __restrict__ nx, const float* __restrict__ ny,
    unsigned int* __restrict__ minp)
{
  __shared__ __align__(16) unsigned short As[2][BM * BK];   // 2 x 32 KB
  __shared__ __align__(16) unsigned short Bs[2][BN * BK];   // 2 x 32 KB
  __shared__ float wmin[8];

  const int tid  = threadIdx.x;
  const int wave = tid >> 6;          // 0..7
  const int lane = tid & 63;

  // XCD-aware bijective remap: 2048 blocks, 8 XCDs, 256 contiguous per XCD.
  const int raw = blockIdx.x;
  const int wg  = (raw & 7) * 256 + (raw >> 3);
  const int by  = wg & 7;             // pred tile fast -> 8 adjacent wg share cand tile
  const int bx  = wg >> 3;            // cand tile
  const int rowA0 = by * BM, rowB0 = bx * BN;
  const int wr = wave >> 2;           // 0..1 : M half   (wave tile 128x64)
  const int wc = wave & 3;            // 0..3 : N quarter

  f32x16 acc[4][2];
  #pragma unroll
  for (int i = 0; i < 4; ++i)
    #pragma unroll
    for (int j = 0; j < 2; ++j)
      #pragma unroll
      for (int r = 0; r < 16; ++r) acc[i][j][r] = 0.f;

  // staging: per operand 32 wave-instrs (8 waves x t=0..3), each 8 rows x 64
  // cols (1 KB). Instr t of wave w covers rows ii*8..ii*8+7 (ii=w*4+t); for
  // those rows (row>>3)&3 == t. lane L -> local row L>>3, stored chunk L&7,
  // source data chunk (L&7) ^ (L>>3) ^ (2t).
  const int rloc = lane >> 3;
  const unsigned short* gA[4]; const unsigned short* gB[4];
  int lofs[4];
  #pragma unroll
  for (int t = 0; t < 4; ++t) {
    const int ii = wave * 4 + t;          // 0..31
    const int cswz = (lane & 7) ^ rloc ^ ((t << 1) & 7);
    gA[t] = Abf + (size_t)(rowA0 + ii * 8 + rloc) * DD + cswz * 8;
    gB[t] = Bbf + (size_t)(rowB0 + ii * 8 + rloc) * DD + cswz * 8;
    lofs[t] = ii * 512;                   // shorts (1 KB per instr)
  }

#define STAGE(s, kt) do { const int _k0 = (kt) * BK;            \
    _Pragma("unroll")                                           \
    for (int _t = 0; _t < 4; ++_t) {                            \
      gload_lds16(gA[_t] + _k0, &As[s][lofs[_t]]);              \
      gload_lds16(gB[_t] + _k0, &Bs[s][lofs[_t]]);              \
    } } while (0)

  // fragment read geometry (32x32x16), new swizzle
  const int col31 = lane & 31, h = lane >> 5;
  const int aBase0 = (wr * 128 + col31) * BK;   // shorts
  const int bBase0 = (wc * 64  + col31) * BK;
  const int swb = (lane & 7) ^ (((lane >> 3) & 3) << 1);
  int swks[4];
  #pragma unroll
  for (int ks = 0; ks < 4; ++ks) swks[ks] = ((ks * 2 + h) ^ swb) * 8;

#define READ(aR, bR, s, ks) do {                                              \
    _Pragma("unroll")                                                         \
    for (int _i = 0; _i < 4; ++_i)                                            \
      aR[_i] = *(const short8*)(&As[s][aBase0 + _i * 32 * BK + swks[ks]]);    \
    _Pragma("unroll")                                                         \
    for (int _j = 0; _j < 2; ++_j)                                            \
      bR[_j] = *(const short8*)(&Bs[s][bBase0 + _j * 32 * BK + swks[ks]]);    \
  } while (0)

#define MFMA8(aR, bR) do {                                                    \
    __builtin_amdgcn_s_setprio(1);                                            \
    _Pragma("unroll")                                                         \
    for (int _i = 0; _i < 4; ++_i)                                            \
      _Pragma("unroll")                                                       \
      for (int _j = 0; _j < 2; ++_j)                                          \
        acc[_i][_j] = __builtin_amdgcn_mfma_f32_32x32x16_bf16(                \
            aR[_i], bR[_j], acc[_i][_j], 0, 0, 0);                            \
    __builtin_amdgcn_s_setprio(0);                                            \
  } while (0)

  STAGE(0, 0);

  #pragma unroll 2
  for (int T = 0; T < NT; ++T) {
    const int s = T & 1;
    // my buf-s loads (issued one tile ago; prologue for T=0) -> landed
    asm volatile("s_waitcnt vmcnt(0)" ::: "memory");
    __builtin_amdgcn_s_barrier();        // everyone's buf-s landed; s^1 free
    __builtin_amdgcn_sched_barrier(0);
    if (T + 1 < NT) STAGE(s ^ 1, T + 1); // flies across this whole tile
    __builtin_amdgcn_sched_barrier(0);

    short8 aX[4], bX[2], aY[4], bY[2];
    READ(aX, bX, s, 0);
    READ(aY, bY, s, 1);
    asm volatile("s_waitcnt lgkmcnt(6)" ::: "memory");   // ks0 landed
    __builtin_amdgcn_sched_barrier(0);
    MFMA8(aX, bX);                                       // ks0
    READ(aX, bX, s, 2);
    asm volatile("s_waitcnt lgkmcnt(6)" ::: "memory");   // ks1 landed
    __builtin_amdgcn_sched_barrier(0);
    MFMA8(aY, bY);                                       // ks1
    READ(aY, bY, s, 3);
    asm volatile("s_waitcnt lgkmcnt(6)" ::: "memory");   // ks2 landed
    __builtin_amdgcn_sched_barrier(0);
    MFMA8(aX, bX);                                       // ks2
    asm volatile("s_waitcnt lgkmcnt(0)" ::: "memory");   // ks3 landed
    __builtin_amdgcn_sched_barrier(0);
    MFMA8(aY, bY);                                       // ks3
  }
#undef STAGE
#undef READ
#undef MFMA8

  // epilogue: d^2 = ||x||^2 + ||y||^2 - 2*dot
  // C/D: col = lane&31, row = (reg&3) + 8*(reg>>2) + 4*h
  float lmin = 3.4e38f;
  #pragma unroll
  for (int i = 0; i < 4; ++i) {
    #pragma unroll
    for (int rq = 0; rq < 4; ++rq) {
      const int mbase = rowA0 + wr * 128 + i * 32 + rq * 8 + h * 4;
      float4 nxv = *(const float4*)(nx + mbase);
      #pragma unroll
      for (int j = 0; j < 2; ++j) {
        const int n = rowB0 + wc * 64 + j * 32 + col31;
        const float nyv = ny[n];
        lmin = fminf(lmin, nxv.x + nyv - 2.0f * acc[i][j][rq * 4 + 0]);
        lmin = fminf(lmin, nxv.y + nyv - 2.0f * acc[i][j][rq * 4 + 1]);
        lmin = fminf(lmin, nxv.z + nyv - 2.0f * acc[i][j][rq * 4 + 2]);
        lmin = fminf(lmin, nxv.w + nyv - 2.0f * acc[i][j][rq * 4 + 3]);
      }
    }
  }
  #pragma unroll
  for (int off = 32; off; off >>= 1) lmin = fminf(lmin, __shfl_down(lmin, off, 64));
  if (lane == 0) wmin[wave] = lmin;
  __syncthreads();
  if (tid == 0) {
    float mn = wmin[0];
    #pragma unroll
    for (int w = 1; w < 8; ++w) mn = fminf(mn, wmin[w]);
    atomicMin(minp, __float_as_uint(fmaxf(mn, 0.0f)));
  }
}

// ---- fallback (only if ws too small): exact fp32 brute force ----
__global__ __launch_bounds__(64) void k_initmin(unsigned int* minp) {
  if (threadIdx.x == 0) *minp = 0x7f800000u;
}

__global__ __launch_bounds__(256) void k_brute(
    const float* __restrict__ pred, const float* __restrict__ cand,
    unsigned int* __restrict__ minp)
{
  __shared__ float yrow[DD];
  __shared__ float wm[4];
  const int c = blockIdx.x;
  for (int i = threadIdx.x; i < DD; i += 256) yrow[i] = cand[(size_t)c * DD + i];
  __syncthreads();
  float lmin = 3.4e38f;
  for (int p = threadIdx.x; p < P; p += 256) {
    const float* xp = pred + (size_t)p * DD;
    float s = 0.f;
    for (int k = 0; k < DD; ++k) { float d = xp[k] - yrow[k]; s = fmaf(d, d, s); }
    lmin = fminf(lmin, s);
  }
  #pragma unroll
  for (int off = 32; off; off >>= 1) lmin = fminf(lmin, __shfl_down(lmin, off, 64));
  if ((threadIdx.x & 63) == 0) wm[threadIdx.x >> 6] = lmin;
  __syncthreads();
  if (threadIdx.x == 0) {
    float mn = fminf(fminf(wm[0], wm[1]), fminf(wm[2], wm[3]));
    atomicMin(minp, __float_as_uint(fmaxf(mn, 0.0f)));
  }
}

__global__ __launch_bounds__(64) void k_finalize(const unsigned int* minp, float* out) {
  if (threadIdx.x == 0) out[0] = sqrtf(__uint_as_float(*minp));
}

extern "C" void kernel_launch(void* const* d_in, const int* in_sizes, int n_in,
                              void* d_out, int out_size, void* d_ws, size_t ws_size,
                              hipStream_t stream) {
  const float* pred = (const float*)d_in[0];
  const float* cand = (const float*)d_in[1];
  float* out = (float*)d_out;

  // ws layout: [0] min-bits | +16 floats: nx[2048] | ny[65536] | Abf bf16[2048*512] | Bbf bf16[65536*512]
  unsigned int* minp = (unsigned int*)d_ws;
  float* wsf = (float*)d_ws;
  float* nx = wsf + 16;
  float* ny = nx + P;
  unsigned short* Abf = (unsigned short*)(ny + R);
  unsigned short* Bbf = Abf + (size_t)P * DD;
  const size_t need = (size_t)(16 + P + R) * 4 + ((size_t)P * DD + (size_t)R * DD) * 2;

  if (ws_size >= need) {
    k_convert<<<2048, 256, 0, stream>>>(pred, cand, Abf, Bbf, nx, ny, minp);
    k_gemm_min<<<(P / BM) * (R / BN), 512, 0, stream>>>(Abf, Bbf, nx, ny, minp);
  } else {
    k_initmin<<<1, 64, 0, stream>>>(minp);
    k_brute<<<R, 256, 0, stream>>>(pred, cand, minp);
  }
  k_finalize<<<1, 64, 0, stream>>>(minp, out);
}